// Round 9
// baseline (264.648 us; speedup 1.0000x reference)
//
#include <hip/hip_runtime.h>
#include <math.h>
#include <stdint.h>

#define BN 4
#define TN 4096
#define EN 1024
#define HN 64
#define BT (BN*TN)

typedef __attribute__((ext_vector_type(8))) short   short8;   // 8 bf16 MFMA frag
typedef __attribute__((ext_vector_type(4))) float   f32x4;    // MFMA acc
typedef __attribute__((ext_vector_type(4))) unsigned short us4;
typedef __attribute__((ext_vector_type(8))) unsigned short us8;

// fp32 -> bf16 RNE
__device__ __forceinline__ unsigned short f2b(float f) {
    union { float f; uint32_t u; } v; v.f = f;
    uint32_t u = v.u;
    return (unsigned short)((u + 0x7FFFu + ((u >> 16) & 1u)) >> 16);
}

__device__ __forceinline__ float fexp2(float x) {
#if __has_builtin(__builtin_amdgcn_exp2f)
    return __builtin_amdgcn_exp2f(x);
#else
    return exp2f(x);
#endif
}

// ---------------------------------------------------------------------------
// W -> bf16. Rows 0-63: Wq scaled by log2(e)/32 (softmax in exp2 domain).
// Rows 64-127: Wk. Rows 128-191: Wv.
// ---------------------------------------------------------------------------
__global__ __launch_bounds__(256)
void wconv(const float* __restrict__ Wq, const float* __restrict__ Wk,
           const float* __restrict__ Wv, unsigned short* __restrict__ W16) {
    const int row = blockIdx.x;
    const int t = threadIdx.x;
    const float* src;
    float sc = 1.0f;
    if (row < 64)       { src = Wq + (size_t)row * EN; sc = 0.045084220f; }
    else if (row < 128) { src = Wk + (size_t)(row - 64) * EN; }
    else                { src = Wv + (size_t)(row - 128) * EN; }
    float4 v = *(const float4*)(src + t * 4);
    us4 p;
    p[0] = f2b(v.x * sc); p[1] = f2b(v.y * sc);
    p[2] = f2b(v.z * sc); p[3] = f2b(v.w * sc);
    *(us4*)&W16[(size_t)row * EN + t * 4] = p;
}

// ---------------------------------------------------------------------------
// QKV projection GEMM, BARRIER-FREE / NO-LDS: both operand frags are
// contiguous in memory, so each wave reads them directly from global.
// A (emb rows, HBM, L1-shared by the 4 wn-waves) as float8 + f2b convert;
// B (W16, L2-broadcast across all blocks) as us8. K-loop 32 steps with
// depth-4 register pipeline (covers ~900cy HBM latency).
// Block 512 thr = 8 waves (2 wm x 4 wn), M-tile 32, grid BT/32 = 512.
// ---------------------------------------------------------------------------
__global__ __launch_bounds__(512)
void qkv_gemm(const float* __restrict__ emb, const unsigned short* __restrict__ W16,
              unsigned short* __restrict__ QK, unsigned short* __restrict__ VT) {
    const int tid = threadIdx.x;
    const int wid = tid >> 6, lane = tid & 63;
    const int c = lane & 15, g = lane >> 4;
    const int wm = wid & 1, wn = wid >> 1;          // 2M x 4N waves
    const int r0 = blockIdx.x * 32;

    const float* aptr = emb + (size_t)(r0 + 16 * wm + c) * EN + 8 * g;
    const unsigned short* bptr0 = W16 + (size_t)(48 * wn + c) * EN + 8 * g;
    const unsigned short* bptr1 = bptr0 + (size_t)16 * EN;
    const unsigned short* bptr2 = bptr0 + (size_t)32 * EN;

    const f32x4 fzero = {0.f, 0.f, 0.f, 0.f};
    f32x4 acc[3];
    #pragma unroll
    for (int j = 0; j < 3; ++j) acc[j] = fzero;

    // depth-4 register pipeline banks
    float4 a0[4], a1[4];
    us8 b0[4], b1[4], b2[4];

    #pragma unroll
    for (int t = 0; t < 4; ++t) {
        a0[t] = *(const float4*)(aptr + 32 * t);
        a1[t] = *(const float4*)(aptr + 32 * t + 4);
        b0[t] = *(const us8*)(bptr0 + 32 * t);
        b1[t] = *(const us8*)(bptr1 + 32 * t);
        b2[t] = *(const us8*)(bptr2 + 32 * t);
    }

    #pragma unroll 4
    for (int t = 0; t < 32; ++t) {
        const int cur = t & 3;   // static after unroll-4
        us8 af;
        af[0] = f2b(a0[cur].x); af[1] = f2b(a0[cur].y);
        af[2] = f2b(a0[cur].z); af[3] = f2b(a0[cur].w);
        af[4] = f2b(a1[cur].x); af[5] = f2b(a1[cur].y);
        af[6] = f2b(a1[cur].z); af[7] = f2b(a1[cur].w);
        const short8 afs = *(const short8*)&af;
        acc[0] = __builtin_amdgcn_mfma_f32_16x16x32_bf16(afs, *(const short8*)&b0[cur], acc[0], 0, 0, 0);
        acc[1] = __builtin_amdgcn_mfma_f32_16x16x32_bf16(afs, *(const short8*)&b1[cur], acc[1], 0, 0, 0);
        acc[2] = __builtin_amdgcn_mfma_f32_16x16x32_bf16(afs, *(const short8*)&b2[cur], acc[2], 0, 0, 0);
        if (t + 4 < 32) {
            const int kn = 32 * (t + 4);
            a0[cur] = *(const float4*)(aptr + kn);
            a1[cur] = *(const float4*)(aptr + kn + 4);
            b0[cur] = *(const us8*)(bptr0 + kn);
            b1[cur] = *(const us8*)(bptr1 + kn);
            b2[cur] = *(const us8*)(bptr2 + kn);
        }
    }

    // epilogue: D row = 4g+j (A side), col = c (B side)  [proven layout]
    #pragma unroll
    for (int nt = 0; nt < 3; ++nt) {
        const int n = 48 * wn + 16 * nt + c;
        const int wsel = n >> 6;
        const int d = n & 63;
        const int rbase = r0 + 16 * wm + 4 * g;
        if (wsel < 2) {
            #pragma unroll
            for (int j = 0; j < 4; ++j)
                QK[(size_t)wsel * BT * HN + (size_t)(rbase + j) * HN + d] =
                    f2b(acc[nt][j]);
        } else {
            const int bb = rbase >> 12;
            const int tt = rbase & 4095;
            us4 p;
            #pragma unroll
            for (int j = 0; j < 4; ++j) p[j] = f2b(acc[nt][j]);
            *(us4*)&VT[(size_t)bb * HN * TN + (size_t)d * TN + tt] = p;
        }
    }
}

// ---------------------------------------------------------------------------
// Flash attention, bf16 MFMA, causal. Q-tile 32, KV-tile 32. Grid 512.
// 256 thr = 4 waves; wave w owns KV-tiles jt = w, w+4, ... independently
// (own LDS slot, NO barriers in main loop). LDS 40KB/block -> 4 blocks/CU
// (16 waves/CU, 4/SIMD) -- TLP hides the staging latency. Defer-max (T13)
// skips the O-rescale when the running max doesn't grow by >8 (exp2 dom.).
// Merge per-wave (m,l,O) partials at the end.
// ---------------------------------------------------------------------------
#define NW 4
#define KSLOT 2304          // 32*72 us
#define VSLOT 2560          // 64*40 us
#define WSLOT (KSLOT+VSLOT) // 4864 us = 9728 B per wave

__global__ __launch_bounds__(256, 4)
void attn(const unsigned short* __restrict__ QK,
          const unsigned short* __restrict__ VT, float* __restrict__ out) {
    __shared__ __align__(16) unsigned short SLAB[NW * WSLOT];  // 38912 B
    __shared__ __align__(16) float MLm[NW][32];
    __shared__ __align__(16) float MLl[NW][32];
    __shared__ __align__(16) float ML2m[32];
    __shared__ __align__(16) float ML2l[32];

    const int tid = threadIdx.x;
    const int w = tid >> 6, lane = tid & 63, c = lane & 15, g = lane >> 4;
    const int bid = blockIdx.x;
    const int b = bid & 3;
    const int qt = (TN / 32 - 1) - (bid >> 2);   // heavy q-tiles first

    const unsigned short* Qg = QK + ((size_t)b * TN + (size_t)qt * 32) * HN;
    const unsigned short* Kg = QK + (size_t)BT * HN + (size_t)b * TN * HN;
    const unsigned short* Vg = VT + (size_t)b * HN * TN;

    unsigned short* Ks = SLAB + w * WSLOT;          // K tile [32][72], P aliases
    unsigned short* Vs = Ks + KSLOT;                // V^T tile [64][40]

    // Q fragments straight from global (L2/L3-resident)
    short8 bq[2][2];
    #pragma unroll
    for (int ct = 0; ct < 2; ++ct)
        #pragma unroll
        for (int ks = 0; ks < 2; ++ks)
            bq[ct][ks] = *(const short8*)&Qg[(size_t)(16 * ct + c) * HN + 32 * ks + 8 * g];

    const f32x4 fzero = {0.f, 0.f, 0.f, 0.f};
    f32x4 o[2][4];
    #pragma unroll
    for (int i = 0; i < 2; ++i)
        #pragma unroll
        for (int j = 0; j < 4; ++j) o[i][j] = fzero;
    float m[2] = {-INFINITY, -INFINITY};
    float l[2] = {0.f, 0.f};

    for (int jt = w; jt <= qt; jt += NW) {
        // ---- stage K [32 k][64 d] and V^T [64 d][32 k] (wave-local)
        #pragma unroll
        for (int i = 0; i < 4; ++i) {
            const int f = lane + 64 * i;
            *(us8*)&Ks[(f >> 3) * 72 + (f & 7) * 8] =
                *(const us8*)&Kg[((size_t)jt * 32 + (f >> 3)) * HN + (f & 7) * 8];
        }
        #pragma unroll
        for (int i = 0; i < 4; ++i) {
            const int f = lane + 64 * i;
            *(us8*)&Vs[(f >> 2) * 40 + (f & 3) * 8] =
                *(const us8*)&Vg[(size_t)(f >> 2) * TN + (size_t)jt * 32 + (f & 3) * 8];
        }

        // ---- S^T[32k][32q] = K . Q^T
        f32x4 st[2][2];   // [kt][ct]
        #pragma unroll
        for (int kt = 0; kt < 2; ++kt)
            #pragma unroll
            for (int ct = 0; ct < 2; ++ct) st[kt][ct] = fzero;
        #pragma unroll
        for (int kt = 0; kt < 2; ++kt) {
            #pragma unroll
            for (int ks = 0; ks < 2; ++ks) {
                short8 ak = *(const short8*)&Ks[(16 * kt + c) * 72 + 32 * ks + 8 * g];
                #pragma unroll
                for (int ct = 0; ct < 2; ++ct)
                    st[kt][ct] = __builtin_amdgcn_mfma_f32_16x16x32_bf16(
                        ak, bq[ct][ks], st[kt][ct], 0, 0, 0);
            }
        }

        // ---- causal mask (diag tile only; k = 16kt+4g+j vs q = 16ct+c)
        if (jt == qt) {
            #pragma unroll
            for (int kt = 0; kt < 2; ++kt)
                #pragma unroll
                for (int ct = 0; ct < 2; ++ct)
                    #pragma unroll
                    for (int j = 0; j < 4; ++j)
                        if (16 * kt + 4 * g + j > 16 * ct + c)
                            st[kt][ct][j] = -INFINITY;
        }

        // ---- online softmax (exp2 domain) with defer-max
        #pragma unroll
        for (int ct = 0; ct < 2; ++ct) {
            float pmax = -INFINITY;
            #pragma unroll
            for (int kt = 0; kt < 2; ++kt)
                #pragma unroll
                for (int j = 0; j < 4; ++j) pmax = fmaxf(pmax, st[kt][ct][j]);
            pmax = fmaxf(pmax, __shfl_xor(pmax, 16));
            pmax = fmaxf(pmax, __shfl_xor(pmax, 32));
            float mn = m[ct];
            float alpha = 1.f;
            const bool defer = __all(pmax - m[ct] <= 8.0f);
            if (!defer) {
                mn = fmaxf(m[ct], pmax);
                alpha = fexp2(m[ct] - mn);
                float a4[4];
                #pragma unroll
                for (int j = 0; j < 4; ++j) a4[j] = __shfl(alpha, 4 * g + j);
                #pragma unroll
                for (int dt = 0; dt < 4; ++dt)
                    #pragma unroll
                    for (int j = 0; j < 4; ++j) o[ct][dt][j] *= a4[j];
                m[ct] = mn;
            }
            float ls = 0.f;
            #pragma unroll
            for (int kt = 0; kt < 2; ++kt)
                #pragma unroll
                for (int j = 0; j < 4; ++j) {
                    float p = fexp2(st[kt][ct][j] - mn);   // <= 2^8 when deferred
                    st[kt][ct][j] = p;
                    ls += p;
                }
            ls += __shfl_xor(ls, 16);
            ls += __shfl_xor(ls, 32);
            l[ct] = l[ct] * alpha + ls;
        }

        // ---- write P[32q][32k] bf16 into the K slot (wave-local alias)
        #pragma unroll
        for (int kt = 0; kt < 2; ++kt)
            #pragma unroll
            for (int ct = 0; ct < 2; ++ct) {
                us4 p;
                #pragma unroll
                for (int j = 0; j < 4; ++j) p[j] = f2b(st[kt][ct][j]);
                *(us4*)&Ks[(16 * ct + c) * 72 + 16 * kt + 4 * g] = p;
            }

        // ---- O += P . V  (single K=32 step)
        {
            short8 pa0 = *(const short8*)&Ks[(c) * 72 + 8 * g];
            short8 pa1 = *(const short8*)&Ks[(16 + c) * 72 + 8 * g];
            #pragma unroll
            for (int dt = 0; dt < 4; ++dt) {
                short8 bv = *(const short8*)&Vs[(16 * dt + c) * 40 + 8 * g];
                o[0][dt] = __builtin_amdgcn_mfma_f32_16x16x32_bf16(pa0, bv, o[0][dt], 0, 0, 0);
                o[1][dt] = __builtin_amdgcn_mfma_f32_16x16x32_bf16(pa1, bv, o[1][dt], 0, 0, 0);
            }
        }
    }

    // ---- publish per-wave m,l
    if (g == 0) {
        MLm[w][c]      = m[0];  MLl[w][c]      = l[0];
        MLm[w][c + 16] = m[1];  MLl[w][c + 16] = l[1];
    }
    __syncthreads();   // all waves past main loop

    // ---- combine m,l across waves (first 32 threads)
    if (tid < 32) {
        const int q = tid;
        float M = MLm[0][q];
        #pragma unroll
        for (int s = 1; s < NW; ++s) M = fmaxf(M, MLm[s][q]);
        float L = 0.f;
        #pragma unroll
        for (int s = 0; s < NW; ++s) L += MLl[s][q] * fexp2(MLm[s][q] - M);
        ML2m[q] = M;
        ML2l[q] = L;
    }
    __syncthreads();

    // ---- scale own O and dump to per-wave f32 slot (aliases KV region)
    float* Oslab = (float*)SLAB;
    float* Ow = Oslab + (size_t)w * (32 * 65);
    #pragma unroll
    for (int qp = 0; qp < 2; ++qp) {
        float mo[4];
        #pragma unroll
        for (int j = 0; j < 4; ++j) mo[j] = __shfl(m[qp], 4 * g + j);
        #pragma unroll
        for (int j = 0; j < 4; ++j) {
            const int q = 16 * qp + 4 * g + j;
            const float sc = fexp2(mo[j] - ML2m[q]);   // exp2(-inf)=0 for idle waves
            #pragma unroll
            for (int dt = 0; dt < 4; ++dt)
                Ow[q * 65 + 16 * dt + c] = o[qp][dt][j] * sc;
        }
    }
    __syncthreads();

    // ---- sum slots, normalize, write out. Wave w owns d-slice [16w,16w+16)
    const int d = 16 * w + c;
    #pragma unroll
    for (int tq = 0; tq < 8; ++tq) {
        const int q = 4 * tq + g;
        float v = 0.f;
        #pragma unroll
        for (int s = 0; s < NW; ++s) v += Oslab[(size_t)s * (32 * 65) + q * 65 + d];
        out[((size_t)b * TN + (size_t)qt * 32 + q) * HN + d] = v / ML2l[q];
    }
}

// ---------------------------------------------------------------------------
extern "C" void kernel_launch(void* const* d_in, const int* in_sizes, int n_in,
                              void* d_out, int out_size, void* d_ws, size_t ws_size,
                              hipStream_t stream) {
    const float* emb = (const float*)d_in[0];
    const float* Wq  = (const float*)d_in[1];
    const float* Wk  = (const float*)d_in[2];
    const float* Wv  = (const float*)d_in[3];
    float* out = (float*)d_out;

    unsigned short* ws  = (unsigned short*)d_ws;
    unsigned short* W16 = ws;                                // [192][1024]   384 KB
    unsigned short* QK  = ws + 196608;                       // [2][BT][64]   4 MB
    unsigned short* VT  = ws + 196608 + 2 * (size_t)BT * HN; // [4][64][4096] 2 MB

    wconv<<<192, 256, 0, stream>>>(Wq, Wk, Wv, W16);
    qkv_gemm<<<BT / 32, 512, 0, stream>>>(emb, W16, QK, VT);
    attn<<<BN * (TN / 32), 256, 0, stream>>>(QK, VT, out);
}